// Round 1
// baseline (204.477 us; speedup 1.0000x reference)
//
#include <hip/hip_runtime.h>
#include <hip/hip_bf16.h>
#include <stdint.h>
#include <stddef.h>

#define T_LEN   2048
#define C_IN_   512
#define D_MODEL_ 1024
#define B_SZ    32

typedef __hip_bfloat16 bf16;
typedef __attribute__((ext_vector_type(8))) short short8;
typedef __attribute__((ext_vector_type(4))) float f32x4;

// ---------------------------------------------------------------------------
// async global->LDS, 16B per lane (linear dest: wave-uniform base + lane*16)
// ---------------------------------------------------------------------------
__device__ __forceinline__ void gload16(const void* g, void* l) {
    __builtin_amdgcn_global_load_lds(
        (const __attribute__((address_space(1))) uint32_t*)g,
        (__attribute__((address_space(3))) uint32_t*)l, 16, 0, 0);
}

// ---------------------------------------------------------------------------
// Kernel 1: W (fp32 [1024][512]) -> bf16, same layout
// ---------------------------------------------------------------------------
__global__ void wconv_kernel(const float* __restrict__ W, bf16* __restrict__ Wb) {
    int i = blockIdx.x * 256 + threadIdx.x;       // 131072 float4 units
    float4 v = ((const float4*)W)[i];
    bf16* o = Wb + (size_t)i * 4;
    o[0] = __float2bfloat16(v.x);
    o[1] = __float2bfloat16(v.y);
    o[2] = __float2bfloat16(v.z);
    o[3] = __float2bfloat16(v.w);
}

// ---------------------------------------------------------------------------
// Kernel 2: bidirectional EWMA, exact 3-level scan, output bf16 A[M=b*T+t][c]
// block = 1024 threads = 16 waves; wave = 2 rows (b,c); lane&31 = 64-chunk idx
// ---------------------------------------------------------------------------
__global__ __launch_bounds__(1024)
void ewma_kernel(const float* __restrict__ x, bf16* __restrict__ A) {
    const int tid  = threadIdx.x;
    const int wid  = tid >> 6;          // 0..15
    const int lane = tid & 63;
    const int half = lane >> 5;         // 0,1 -> which row of the wave
    const int j    = lane & 31;         // chunk (64 t's each)
    const int b    = blockIdx.x >> 4;   // 0..31
    const int cg   = blockIdx.x & 15;   // 0..15 (32 channels per block)
    const int c_local = (wid << 1) | half;       // 0..31
    const int c    = (cg << 5) + c_local;

    const float AL = 0.1f, OM = 0.9f;
    const float Q  = 1.179018457773862e-3f;      // 0.9^64

    // ---- P1: load 64 consecutive x values into registers
    float xr[64];
    const float4* xp = (const float4*)(x + (size_t)(b * C_IN_ + c) * T_LEN + j * 64);
    #pragma unroll
    for (int i = 0; i < 16; ++i) {
        float4 v = xp[i];
        xr[4*i+0] = v.x; xr[4*i+1] = v.y; xr[4*i+2] = v.z; xr[4*i+3] = v.w;
    }

    // ---- P2: local fwd scan (zero carry), end value g. t=0 special: f0 = x0.
    float g = (j == 0) ? xr[0] : AL * xr[0];
    #pragma unroll
    for (int i = 1; i < 64; ++i) g = fmaf(OM, g, AL * xr[i]);

    // ---- P3: Kogge-Stone carry scan across the 32 chunks (width-32 groups)
    float F = g, coef = Q;
    #pragma unroll
    for (int d = 1; d < 32; d <<= 1) {
        float up = __shfl_up(F, d, 32);
        F += (j >= d) ? coef * up : 0.0f;
        coef *= coef;
    }
    float carry = __shfl_up(F, 1, 32);           // true f at t0-1
    if (j == 0) carry = 0.0f;

    // ---- P4: seeded fwd recompute, in place (xr becomes f)
    xr[0] = (j == 0) ? xr[0] : fmaf(OM, carry, AL * xr[0]);
    #pragma unroll
    for (int i = 1; i < 64; ++i) xr[i] = fmaf(OM, xr[i-1], AL * xr[i]);

    // ---- P5: local bwd scan built from f only: inc[t] = alpha*x_t = f[t]-0.9f[t-1]
    //          specials: t=0 -> alpha*f[0]; t=T-1 -> 10*(f-0.9f_prev) = x_{T-1}
    float h;
    {
        float incL = xr[63] - OM * xr[62];
        if (j == 31) incL *= 10.0f;
        h = incL;
        #pragma unroll
        for (int i = 62; i >= 1; --i) h = fmaf(OM, h, xr[i] - OM * xr[i-1]);
        float inc0 = (j == 0) ? AL * xr[0] : (xr[0] - OM * carry);
        h = fmaf(OM, h, inc0);
    }

    // ---- P6: bwd carry scan (toward higher j)
    float Bv = h; coef = Q;
    #pragma unroll
    for (int d = 1; d < 32; d <<= 1) {
        float dn = __shfl_down(Bv, d, 32);
        Bv += (j < 32 - d) ? coef * dn : 0.0f;
        coef *= coef;
    }
    float bnext = __shfl_down(Bv, 1, 32);        // true b at t0+64
    if (j == 31) bnext = 0.0f;

    // ---- P7: final bwd recompute + combine, in place (xr becomes 0.5*(f+b))
    {
        float bp = bnext;
        float incL = xr[63] - OM * xr[62];
        if (j == 31) incL *= 10.0f;
        float bb = fmaf(OM, bp, incL);
        xr[63] = 0.5f * (xr[63] + bb);
        bp = bb;
        #pragma unroll
        for (int i = 62; i >= 1; --i) {
            float inc = xr[i] - OM * xr[i-1];
            bb = fmaf(OM, bp, inc);
            xr[i] = 0.5f * (xr[i] + bb);
            bp = bb;
        }
        float inc0 = (j == 0) ? AL * xr[0] : (xr[0] - OM * carry);
        bb = fmaf(OM, bp, inc0);
        xr[0] = 0.5f * (xr[0] + bb);
    }

    // ---- P8: LDS transpose stage -> coalesced 64B-line bf16 writes
    // staging [j][ii][c_local], XOR-swizzled by (j&7)<<3 to break j-bank aliasing
    __shared__ bf16 stg[32 * 16 * 32];           // 32KB
    const size_t outbase = (size_t)(b * T_LEN) * C_IN_ + (cg << 5);
    #pragma unroll
    for (int grp = 0; grp < 4; ++grp) {
        __syncthreads();
        #pragma unroll
        for (int ii = 0; ii < 16; ++ii) {
            int elem = ((j * 16 + ii) * 32 + c_local) ^ ((j & 7) << 3);
            stg[elem] = __float2bfloat16(xr[grp * 16 + ii]);
        }
        __syncthreads();
        #pragma unroll
        for (int r = 0; r < 2; ++r) {
            int u   = tid * 2 + r;               // 2048 16B-units
            int jj  = u >> 6;
            int ii  = (u >> 2) & 15;
            int oct = u & 3;
            int elem = ((jj * 512) + (ii * 32) + (oct * 8)) ^ ((jj & 7) << 3);
            float4 v = *(const float4*)&stg[elem];
            int t = jj * 64 + grp * 16 + ii;
            *(float4*)(A + outbase + (size_t)t * C_IN_ + oct * 8) = v;
        }
    }
}

// ---------------------------------------------------------------------------
// Kernel 3: GEMM  out[m][n] = sum_k A[m][k] * W[n][k] + bias[n]
// M=65536 N=1024 K=512; 128x128 tile, BK=64, 4 waves, 4x4 16x16 frags/wave
// ---------------------------------------------------------------------------
__global__ __launch_bounds__(256)
void gemm_kernel(const bf16* __restrict__ Amat, const bf16* __restrict__ Wb,
                 const float* __restrict__ bias, float* __restrict__ out) {
    constexpr int K = C_IN_, N = D_MODEL_, BK = 64;
    __shared__ bf16 As[128 * BK];   // [m][k] 16KB
    __shared__ bf16 Bs[128 * BK];   // [n][k] 16KB
    const int tid = threadIdx.x;
    const int wid = tid >> 6, lane = tid & 63;
    const int nb = blockIdx.x & 7, mb = blockIdx.x >> 3;
    const int m0 = mb * 128, n0 = nb * 128;
    const int wr = wid >> 1, wc = wid & 1;       // wave quadrant (64x64)
    const int lrow = lane & 15, lk = (lane >> 4) * 8;

    f32x4 acc[4][4];
    #pragma unroll
    for (int i = 0; i < 4; ++i)
        #pragma unroll
        for (int q = 0; q < 4; ++q) acc[i][q] = (f32x4){0.f, 0.f, 0.f, 0.f};

    for (int kt = 0; kt < K; kt += BK) {
        const char* Ag = (const char*)(Amat + (size_t)m0 * K + kt);
        const char* Bg = (const char*)(Wb   + (size_t)n0 * K + kt);
        #pragma unroll
        for (int r = 0; r < 4; ++r) {
            int fb  = r * 4096 + tid * 16;       // flat byte in 16KB tile
            int row = fb >> 7;                   // 128B per row
            int kb  = fb & 127;
            gload16(Ag + (size_t)row * (K * 2) + kb, (char*)As + fb);
            gload16(Bg + (size_t)row * (K * 2) + kb, (char*)Bs + fb);
        }
        __syncthreads();
        #pragma unroll
        for (int ks = 0; ks < 2; ++ks) {
            short8 af[4], bff[4];
            #pragma unroll
            for (int mf = 0; mf < 4; ++mf)
                af[mf] = *(const short8*)&As[(wr * 64 + mf * 16 + lrow) * BK + ks * 32 + lk];
            #pragma unroll
            for (int nf = 0; nf < 4; ++nf)
                bff[nf] = *(const short8*)&Bs[(wc * 64 + nf * 16 + lrow) * BK + ks * 32 + lk];
            #pragma unroll
            for (int mf = 0; mf < 4; ++mf)
                #pragma unroll
                for (int nf = 0; nf < 4; ++nf)
                    acc[mf][nf] = __builtin_amdgcn_mfma_f32_16x16x32_bf16(
                        af[mf], bff[nf], acc[mf][nf], 0, 0, 0);
        }
        __syncthreads();
    }
    // epilogue: C mapping col=lane&15, row=(lane>>4)*4+reg
    #pragma unroll
    for (int mf = 0; mf < 4; ++mf) {
        #pragma unroll
        for (int nf = 0; nf < 4; ++nf) {
            int mrow0 = m0 + wr * 64 + mf * 16 + (lane >> 4) * 4;
            int ncol  = n0 + wc * 64 + nf * 16 + (lane & 15);
            float bv = bias[ncol];
            #pragma unroll
            for (int r = 0; r < 4; ++r)
                out[(size_t)(mrow0 + r) * N + ncol] = acc[mf][nf][r] + bv;
        }
    }
}

// ---------------------------------------------------------------------------
extern "C" void kernel_launch(void* const* d_in, const int* in_sizes, int n_in,
                              void* d_out, int out_size, void* d_ws, size_t ws_size,
                              hipStream_t stream) {
    const float* x    = (const float*)d_in[0];
    const float* W    = (const float*)d_in[1];
    const float* bias = (const float*)d_in[2];
    float* out = (float*)d_out;

    bf16* Wb   = (bf16*)d_ws;                          // 1MB
    bf16* Amat = (bf16*)((char*)d_ws + (1 << 21));     // 64MB at +2MB

    hipLaunchKernelGGL(wconv_kernel, dim3(512), dim3(256), 0, stream, W, Wb);
    hipLaunchKernelGGL(ewma_kernel, dim3(B_SZ * 16), dim3(1024), 0, stream, x, Amat);
    hipLaunchKernelGGL(gemm_kernel, dim3((B_SZ * T_LEN / 128) * (D_MODEL_ / 128)),
                       dim3(256), 0, stream, Amat, Wb, bias, out);
}